// Round 1
// baseline (75.315 us; speedup 1.0000x reference)
//
#include <hip/hip_runtime.h>

// WFVAE encode: 3-level 2D Haar approximation == 8x8 box sum * 0.125.
// x:   [96, 1024, 1024] f32   (96 = 2*3*16 leading dims flattened)
// out: [96,  128,  128] f32
// out[n,oy,ox] = 0.125 * sum_{dy<8,dx<8} x[n, 8*oy+dy, 8*ox+dx]
//
// Mapping: one wave per output row. Each lane owns 2 adjacent outputs,
// i.e. 16 consecutive input floats (64 B = one cache line) per input row.
// Wave covers 64*64 B = 4096 B = one full input row per iteration ->
// perfectly coalesced float4 loads.

__global__ __launch_bounds__(256) void WFVAE_85796266705018_kernel(
        const float* __restrict__ x, float* __restrict__ out) {
    const int wavesPerBlock = blockDim.x >> 6;               // 4
    const int gwave = blockIdx.x * wavesPerBlock + (threadIdx.x >> 6);
    const int lane  = threadIdx.x & 63;

    // gwave in [0, 96*128): n = image, oy = output row
    const int n  = gwave >> 7;
    const int oy = gwave & 127;

    const float* row0 = x + ((size_t)n * 1024 + (size_t)oy * 8) * 1024
                          + (size_t)lane * 16;

    float s0 = 0.0f, s1 = 0.0f;
#pragma unroll
    for (int dy = 0; dy < 8; ++dy) {
        const float4* p = (const float4*)(row0 + (size_t)dy * 1024);
        float4 a = p[0];
        float4 b = p[1];
        float4 c = p[2];
        float4 d = p[3];
        s0 += (a.x + a.y) + (a.z + a.w) + (b.x + b.y) + (b.z + b.w);
        s1 += (c.x + c.y) + (c.z + c.w) + (d.x + d.y) + (d.z + d.w);
    }

    float2 o = make_float2(s0 * 0.125f, s1 * 0.125f);
    *(float2*)(out + ((size_t)n * 128 + oy) * 128 + (size_t)lane * 2) = o;
}

extern "C" void kernel_launch(void* const* d_in, const int* in_sizes, int n_in,
                              void* d_out, int out_size, void* d_ws, size_t ws_size,
                              hipStream_t stream) {
    const float* x = (const float*)d_in[0];
    float* out = (float*)d_out;

    // 96 images * 128 output rows = 12288 waves; 4 waves/block -> 3072 blocks
    const int total_waves = 96 * 128;
    const int block = 256;
    const int grid = total_waves / (block / 64);

    WFVAE_85796266705018_kernel<<<grid, block, 0, stream>>>(x, out);
}

// Round 2
// 67.631 us; speedup vs baseline: 1.1136x; 1.1136x over previous
//
#include <hip/hip_runtime.h>

// WFVAE encode: 3-level 2D Haar approximation == 8x8 box sum * 0.125.
// x:   [96, 1024, 1024] f32   (96 = 2*3*16 leading dims flattened)
// out: [96,  128,  128] f32
// out[n,oy,ox] = 0.125 * sum_{dy<8,dx<8} x[n, 8*oy+dy, 8*ox+dx]
//
// Mapping: one wave per output row (8 input rows of 4 KB each).
// Per load instruction, lane i reads float4 at base + i*16B -> 1024 B
// fully contiguous per instruction (ideal coalescing; each 64 B line
// consumed by 4 lanes of the SAME instruction). Each lane keeps 4
// accumulators (one per 1 KB chunk); a float4 lies entirely inside one
// 8-wide output bucket, shared by lane pairs (2k,2k+1) -> one
// __shfl_xor(1) finishes the reduction. Streaming data -> nontemporal.

typedef float v4f __attribute__((ext_vector_type(4)));

__global__ __launch_bounds__(256) void WFVAE_85796266705018_kernel(
        const float* __restrict__ x, float* __restrict__ out) {
    const int gwave = blockIdx.x * 4 + (threadIdx.x >> 6);
    const int lane  = threadIdx.x & 63;

    const int n  = gwave >> 7;   // image 0..95
    const int oy = gwave & 127;  // output row

    const v4f* base = (const v4f*)(x + ((size_t)n * 1024 + (size_t)oy * 8) * 1024)
                      + lane;

    float s0 = 0.0f, s1 = 0.0f, s2 = 0.0f, s3 = 0.0f;
#pragma unroll
    for (int dy = 0; dy < 8; ++dy) {
        const v4f* p = base + (size_t)dy * 256;   // 256 v4f per 1024-float row
        v4f a = __builtin_nontemporal_load(p);        // chunk 0: bytes [0,1024)
        v4f b = __builtin_nontemporal_load(p + 64);   // chunk 1
        v4f c = __builtin_nontemporal_load(p + 128);  // chunk 2
        v4f d = __builtin_nontemporal_load(p + 192);  // chunk 3
        s0 += (a.x + a.y) + (a.z + a.w);
        s1 += (b.x + b.y) + (b.z + b.w);
        s2 += (c.x + c.y) + (c.z + c.w);
        s3 += (d.x + d.y) + (d.z + d.w);
    }

    // lanes 2k and 2k+1 both hold half of output (chunk*32 + k)
    s0 += __shfl_xor(s0, 1);
    s1 += __shfl_xor(s1, 1);
    s2 += __shfl_xor(s2, 1);
    s3 += __shfl_xor(s3, 1);

    float* orow = out + ((size_t)n * 128 + oy) * 128;
    if ((lane & 1) == 0) {
        const int k = lane >> 1;  // 0..31
        orow[k]      = s0 * 0.125f;
        orow[32 + k] = s1 * 0.125f;
        orow[64 + k] = s2 * 0.125f;
        orow[96 + k] = s3 * 0.125f;
    }
}

extern "C" void kernel_launch(void* const* d_in, const int* in_sizes, int n_in,
                              void* d_out, int out_size, void* d_ws, size_t ws_size,
                              hipStream_t stream) {
    const float* x = (const float*)d_in[0];
    float* out = (float*)d_out;

    // 96 images * 128 output rows = 12288 waves; 4 waves/block -> 3072 blocks
    const int total_waves = 96 * 128;
    const int block = 256;
    const int grid = total_waves / (block / 64);

    WFVAE_85796266705018_kernel<<<grid, block, 0, stream>>>(x, out);
}